// Round 6
// baseline (1276.351 us; speedup 1.0000x reference)
//
#include <hip/hip_runtime.h>
#include <stdint.h>

// ---------------- Threefry-2x32-20 (JAX-compatible) ----------------
#ifdef __HIP_DEVICE_COMPILE__
#define ROTL32(x, R) __builtin_amdgcn_alignbit((x), (x), 32u - (R))
#else
#define ROTL32(x, R) (((x) << (R)) | ((x) >> (32 - (R))))
#endif
#define TF_ROUND(x0, x1, R) { x0 += x1; x1 = ROTL32(x1, R); x1 ^= x0; }

__host__ __device__ __forceinline__ void tf2x32(uint32_t k0, uint32_t k1,
                                                uint32_t x0, uint32_t x1,
                                                uint32_t& o0, uint32_t& o1) {
  uint32_t k2 = k0 ^ k1 ^ 0x1BD11BDAu;
  x0 += k0; x1 += k1;
  TF_ROUND(x0, x1, 13) TF_ROUND(x0, x1, 15) TF_ROUND(x0, x1, 26) TF_ROUND(x0, x1, 6)
  x0 += k1; x1 += k2 + 1u;
  TF_ROUND(x0, x1, 17) TF_ROUND(x0, x1, 29) TF_ROUND(x0, x1, 16) TF_ROUND(x0, x1, 24)
  x0 += k2; x1 += k0 + 2u;
  TF_ROUND(x0, x1, 13) TF_ROUND(x0, x1, 15) TF_ROUND(x0, x1, 26) TF_ROUND(x0, x1, 6)
  x0 += k0; x1 += k1 + 3u;
  TF_ROUND(x0, x1, 17) TF_ROUND(x0, x1, 29) TF_ROUND(x0, x1, 16) TF_ROUND(x0, x1, 24)
  x0 += k1; x1 += k2 + 4u;
  TF_ROUND(x0, x1, 13) TF_ROUND(x0, x1, 15) TF_ROUND(x0, x1, 26) TF_ROUND(x0, x1, 6)
  x0 += k2; x1 += k0 + 5u;
  o0 = x0; o1 = x1;
}

typedef __attribute__((ext_vector_type(8))) short  short8;
typedef __attribute__((ext_vector_type(4))) float  f32x4;

#define NSAMP 131072
#define DDIM  256
#define ROWS  32          // samples per block
#define MT    2           // 16-row MFMA tiles per wave (ROWS/16)
#define NT    2           // 16-col MFMA tiles per wave (8 waves x 32 cols)

// partitionable 32-bit random_bits: counter i (hi=0), bits = o0 ^ o1
__device__ __forceinline__ uint32_t tf_bits(uint32_t k0, uint32_t k1, uint32_t ctr) {
  uint32_t o0, o1;
  tf2x32(k0, k1, 0u, ctr, o0, o1);
  return o0 ^ o1;
}

// Rare path (p ~ 2e-5 per element): staged f32 1/(1+exp(-x)) with
// correctly-rounded f32 exp via f64 — matches reference elementwise sigmoid.
__device__ __attribute__((noinline)) float sigmoid_exact(float x) {
  float e32 = (float)exp(-(double)x);   // correctly-rounded f32 exp
  return 1.0f / (1.0f + e32);           // IEEE f32 div (no fast-math)
}

__device__ __forceinline__ int zaddr(int row, int d) {
  // ROWS x 256 bf16, XOR-swizzled at 16B blocks for conflict-light ds_read_b128
  return row * 256 + ((((d >> 3) ^ (row & 7)) << 3)) + (d & 7);
}

__host__ __device__ __forceinline__ unsigned short f32_to_bf16_rne(float f) {
  uint32_t u; __builtin_memcpy(&u, &f, 4);
  u += 0x7FFFu + ((u >> 16) & 1u);
  return (unsigned short)(u >> 16);
}

// Pre-swizzle W into MFMA B-fragment order, split bf16 hi/lo (exact sum).
// frag index t = ((ntile*8 + kc)*64 + lane)*8 + j  ->  W[kc*32 + (lane>>4)*8 + j][ntile*16 + (lane&15)]
__global__ void prep_w(const float* __restrict__ W,
                       unsigned short* __restrict__ wh, unsigned short* __restrict__ wl) {
  int t = blockIdx.x * 256 + threadIdx.x;          // 0..65535
  int ntile = t >> 12, kc = (t >> 9) & 7, lane = (t >> 3) & 63, j = t & 7;
  int k   = kc * 32 + ((lane >> 4) << 3) + j;
  int col = ntile * 16 + (lane & 15);
  float wv = W[k * 256 + col];
  unsigned short hi = f32_to_bf16_rne(wv);
  float hif; { uint32_t hu = ((uint32_t)hi) << 16; __builtin_memcpy(&hif, &hu, 4); }
  wh[t] = hi;
  wl[t] = f32_to_bf16_rne(wv - hif);               // exact residual (Sterbenz)
}

// R6: R5's interleaved structure + the CORRECT register budget.
// DISCOVERY (R2/R3/R5 VGPR counts): hipcc treats __launch_bounds__ 2nd arg
// with CUDA semantics = min BLOCKS per CU, not waves/EU:
//   (512,8) -> 16 waves/SIMD -> 512/16 = 32 VGPR (R2, measured 32)
//   (512,6) -> 12 waves/SIMD -> 512/12 = 42     (R3-R5, measured 40)
// So R5's nt-interleave (matmul(nt=1) under sampling(nt=0) threefry VALU —
// targeting the ~480us issue-floor vs ~990us measured = ~50% stall gap)
// ran with 40 regs and spilled 2.3 GB. Here: (512,3) -> 6 waves/SIMD ->
// 85-VGPR budget, 3 blocks/CU (LDS 97.5 <= 160 KB), 24 waves/CU.
__global__ __launch_bounds__(512, 3)
void rbm_kernel(const float* __restrict__ h,
                const unsigned short* __restrict__ Wh,
                const unsigned short* __restrict__ Wl,
                float* __restrict__ out,
                uint32_t i0, uint32_t i1, uint32_t l0, uint32_t l1) {
  __shared__ unsigned short Zbuf[2][ROWS * 256];   // 2 x 16 KB
  __shared__ uint32_t kbuf[22];                    // [0..1]=init key, [2+2s..]=step s key
  const int tid  = threadIdx.x;
  const int w    = tid >> 6;        // wave 0..7 -> cols [32w, 32w+32)
  const int lane = tid & 63;
  const int q    = lane >> 4;
  const int l15  = lane & 15;
  const int b    = blockIdx.x;
  const int cb   = w * 32;
  const int nbase = b * ROWS;

  if (tid < 11) {
    uint32_t a, c;
    tf2x32(l0, l1, 0u, (uint32_t)tid - 1u, a, c);  // step key E_{kloop}(0, tid-1)
    if (tid == 0) { a = i0; c = i1; }              // init key
    kbuf[2 * tid]     = a;
    kbuf[2 * tid + 1] = c;
  }

  float hreg[NT];
  #pragma unroll
  for (int nt = 0; nt < NT; ++nt) hreg[nt] = h[cb + nt * 16 + l15];

  f32x4 acc[MT][NT];
  #pragma unroll
  for (int mt = 0; mt < MT; ++mt)
    #pragma unroll
    for (int nt = 0; nt < NT; ++nt) acc[mt][nt] = (f32x4){0.f, 0.f, 0.f, 0.f};

  // acc[.][nt_] = Z @ W for this wave's col-tile nt_ (bf16 hi+lo, exact sum)
  auto matmul_nt = [&](const unsigned short* Zin, int nt_) {
    #pragma unroll
    for (int mt = 0; mt < MT; ++mt) acc[mt][nt_] = (f32x4){0.f, 0.f, 0.f, 0.f};
    #pragma unroll 2
    for (int kc = 0; kc < 8; ++kc) {
      short8 a[MT];
      #pragma unroll
      for (int mt = 0; mt < MT; ++mt) {
        int row = mt * 16 + l15;                       // A: m = lane&15
        int idx = row * 256 + ((((kc * 4 + q) ^ (row & 7)) << 3));  // k-chunk block
        a[mt] = *(const short8*)(Zin + idx);
      }
      int fidx = ((((NT * w + nt_) * 8 + kc) * 64) + lane) * 8;
      short8 bh = *(const short8*)(Wh + fidx);
      short8 bl = *(const short8*)(Wl + fidx);
      #pragma unroll
      for (int mt = 0; mt < MT; ++mt)
        acc[mt][nt_] = __builtin_amdgcn_mfma_f32_16x16x32_bf16(a[mt], bh, acc[mt][nt_], 0, 0, 0);
      #pragma unroll
      for (int mt = 0; mt < MT; ++mt)
        acc[mt][nt_] = __builtin_amdgcn_mfma_f32_16x16x32_bf16(a[mt], bl, acc[mt][nt_], 0, 0, 0);
    }
  };

  // Bernoulli-sample this wave's col-tile nt_ into Zout (8 elems/thread)
  auto sample_nt = [&](unsigned short* Zout, uint32_t kk0, uint32_t kk1,
                       bool isInit, int nt_) {
    const int dcol = cb + nt_ * 16 + l15;
    #pragma unroll
    for (int mt = 0; mt < MT; ++mt) {
      const int rowb = mt * 16 + q * 4;              // C/D: row = quad*4 + reg
      const uint32_t cbase = (uint32_t)((nbase + rowb) * 256 + dcol);
      uint32_t bits[4];
      #pragma unroll
      for (int r = 0; r < 4; ++r) bits[r] = tf_bits(kk0, kk1, cbase + 256u * (uint32_t)r);
      #pragma unroll
      for (int r = 0; r < 4; ++r) {
        float u = __uint_as_float((bits[r] >> 9) | 0x3f800000u) - 1.0f;
        float x = isInit ? 0.0f : (acc[mt][nt_][r] + hreg[nt_]);
        float x2 = x * x;
        float sg = fmaf(x, fmaf(x2, fmaf(x2, 2.0833333333333333e-03f,
                                             -2.0833333333333332e-02f), 0.25f), 0.5f);
        if (__builtin_expect((fabsf(u - sg) <= 1e-5f) || (fabsf(x) >= 0.12f), 0))
          sg = sigmoid_exact(x);
        Zout[zaddr(rowb + r, dcol)] = (u < sg) ? (unsigned short)0x3F80u : (unsigned short)0u;
      }
    }
  };

  __syncthreads();   // kbuf visible to all waves

  // s = -1: bernoulli init (x = 0 -> p = 0.5 exactly) writes Z[0];
  // s = 0..9: per nt: matmul(nt) reads Z[s&1], sampling(nt) writes Z[(s+1)&1]
  //           (nt=1 matmul overlaps nt=0 sampling — independent);
  // s = 10: final matmul only (reads Z[0] = final z) for the energy.
  #pragma unroll 1
  for (int s = -1; s <= 10; ++s) {
    const unsigned short* Zin = Zbuf[s & 1];
    unsigned short* Zout = Zbuf[(s + 1) & 1];
    if (s < 0) {
      const uint32_t kk0 = kbuf[0], kk1 = kbuf[1];
      #pragma unroll
      for (int nt = 0; nt < NT; ++nt) sample_nt(Zout, kk0, kk1, true, nt);
    } else if (s < 10) {
      const uint32_t kk0 = kbuf[2 * (s + 1)];        // uniform LDS broadcast
      const uint32_t kk1 = kbuf[2 * (s + 1) + 1];
      #pragma unroll
      for (int nt = 0; nt < NT; ++nt) {
        matmul_nt(Zin, nt);
        sample_nt(Zout, kk0, kk1, false, nt);
      }
    } else {
      #pragma unroll
      for (int nt = 0; nt < NT; ++nt) matmul_nt(Zin, nt);
    }
    __syncthreads();   // sampling(s) writes visible before matmul(s+1) reads
  }

  // energy[n] = -(sum_d z*h + sum_d (z@W)*z); acc holds y = z@W, z in Zbuf[0]
  const unsigned short* Zfin = Zbuf[0];
  float rs[MT][4];
  #pragma unroll
  for (int mt = 0; mt < MT; ++mt) {
    #pragma unroll
    for (int r = 0; r < 4; ++r) {
      const int row = mt * 16 + q * 4 + r;
      float p = 0.f;
      #pragma unroll
      for (int nt = 0; nt < NT; ++nt) {
        const int dcol = cb + nt * 16 + l15;
        float z = (Zfin[zaddr(row, dcol)] != 0) ? 1.0f : 0.0f;
        p += z * (hreg[nt] + acc[mt][nt][r]);
      }
      p += __shfl_xor(p, 1);
      p += __shfl_xor(p, 2);
      p += __shfl_xor(p, 4);
      p += __shfl_xor(p, 8);
      rs[mt][r] = p;   // 16-lane group sum (this wave's 32 cols)
    }
  }
  __syncthreads();                      // Zbuf[1] reads long done -> reuse as esum
  float* esum = (float*)Zbuf[1];        // esum[row*8 + w]
  #pragma unroll
  for (int mt = 0; mt < MT; ++mt)
    #pragma unroll
    for (int r = 0; r < 4; ++r)
      if (l15 == 0) esum[(mt * 16 + q * 4 + r) * 8 + w] = rs[mt][r];
  __syncthreads();
  if (tid < ROWS) {
    float e = 0.f;
    #pragma unroll
    for (int j = 0; j < 8; ++j) e += esum[tid * 8 + j];
    out[nbase + tid] = -e;
  }
}

extern "C" void kernel_launch(void* const* d_in, const int* in_sizes, int n_in,
                              void* d_out, int out_size, void* d_ws, size_t ws_size,
                              hipStream_t stream) {
  const float* h = (const float*)d_in[0];
  const float* W = (const float*)d_in[1];
  float* out = (float*)d_out;
  unsigned short* wh = (unsigned short*)d_ws;      // 65536 bf16 = 128 KB
  unsigned short* wl = wh + 65536;                 // +128 KB

  prep_w<<<256, 256, 0, stream>>>(W, wh, wl);

  // Host-side key derivation (jax_threefry_partitionable=True semantics):
  // root = key(42) = (0,42); split -> k_init = E(0,0), k_loop = E(0,1).
  // Step keys are derived on-device (threads 0..10 per block, once).
  uint32_t i0, i1, l0, l1;
  tf2x32(0u, 42u, 0u, 0u, i0, i1);
  tf2x32(0u, 42u, 0u, 1u, l0, l1);

  rbm_kernel<<<NSAMP / ROWS, 512, 0, stream>>>(h, wh, wl, out, i0, i1, l0, l1);
}

// Round 7
// 962.569 us; speedup vs baseline: 1.3260x; 1.3260x over previous
//
#include <hip/hip_runtime.h>
#include <stdint.h>

// ---------------- Threefry-2x32-20 (JAX-compatible) ----------------
#ifdef __HIP_DEVICE_COMPILE__
#define ROTL32(x, R) __builtin_amdgcn_alignbit((x), (x), 32u - (R))
#else
#define ROTL32(x, R) (((x) << (R)) | ((x) >> (32 - (R))))
#endif
#define TF_ROUND(x0, x1, R) { x0 += x1; x1 = ROTL32(x1, R); x1 ^= x0; }

__host__ __device__ __forceinline__ void tf2x32(uint32_t k0, uint32_t k1,
                                                uint32_t x0, uint32_t x1,
                                                uint32_t& o0, uint32_t& o1) {
  uint32_t k2 = k0 ^ k1 ^ 0x1BD11BDAu;
  x0 += k0; x1 += k1;
  TF_ROUND(x0, x1, 13) TF_ROUND(x0, x1, 15) TF_ROUND(x0, x1, 26) TF_ROUND(x0, x1, 6)
  x0 += k1; x1 += k2 + 1u;
  TF_ROUND(x0, x1, 17) TF_ROUND(x0, x1, 29) TF_ROUND(x0, x1, 16) TF_ROUND(x0, x1, 24)
  x0 += k2; x1 += k0 + 2u;
  TF_ROUND(x0, x1, 13) TF_ROUND(x0, x1, 15) TF_ROUND(x0, x1, 26) TF_ROUND(x0, x1, 6)
  x0 += k0; x1 += k1 + 3u;
  TF_ROUND(x0, x1, 17) TF_ROUND(x0, x1, 29) TF_ROUND(x0, x1, 16) TF_ROUND(x0, x1, 24)
  x0 += k1; x1 += k2 + 4u;
  TF_ROUND(x0, x1, 13) TF_ROUND(x0, x1, 15) TF_ROUND(x0, x1, 26) TF_ROUND(x0, x1, 6)
  x0 += k2; x1 += k0 + 5u;
  o0 = x0; o1 = x1;
}

typedef __attribute__((ext_vector_type(8))) short  short8;
typedef __attribute__((ext_vector_type(4))) float  f32x4;

#define NSAMP 131072
#define DDIM  256
#define ROWS  32          // samples per block
#define MT    2           // 16-row MFMA tiles per wave (ROWS/16)
#define NT    4           // 16-col MFMA tiles per wave (4 waves x 64 cols)

// partitionable 32-bit random_bits: counter i (hi=0), bits = o0 ^ o1
__device__ __forceinline__ uint32_t tf_bits(uint32_t k0, uint32_t k1, uint32_t ctr) {
  uint32_t o0, o1;
  tf2x32(k0, k1, 0u, ctr, o0, o1);
  return o0 ^ o1;
}

// Rare path (p ~ 2e-5 per element): staged f32 1/(1+exp(-x)) with
// correctly-rounded f32 exp via f64 — matches reference elementwise sigmoid.
__device__ __attribute__((noinline)) float sigmoid_exact(float x) {
  float e32 = (float)exp(-(double)x);   // correctly-rounded f32 exp
  return 1.0f / (1.0f + e32);           // IEEE f32 div (no fast-math)
}

__device__ __forceinline__ int zaddr(int row, int d) {
  // ROWS x 256 bf16, XOR-swizzled at 16B blocks for conflict-light ds_read_b128
  return row * 256 + ((((d >> 3) ^ (row & 7)) << 3)) + (d & 7);
}

__host__ __device__ __forceinline__ unsigned short f32_to_bf16_rne(float f) {
  uint32_t u; __builtin_memcpy(&u, &f, 4);
  u += 0x7FFFu + ((u >> 16) & 1u);
  return (unsigned short)(u >> 16);
}

// Pre-swizzle W into MFMA B-fragment order, split bf16 hi/lo (exact sum).
// frag index t = ((ntile*8 + kc)*64 + lane)*8 + j  ->  W[kc*32 + (lane>>4)*8 + j][ntile*16 + (lane&15)]
__global__ void prep_w(const float* __restrict__ W,
                       unsigned short* __restrict__ wh, unsigned short* __restrict__ wl) {
  int t = blockIdx.x * 256 + threadIdx.x;          // 0..65535
  int ntile = t >> 12, kc = (t >> 9) & 7, lane = (t >> 3) & 63, j = t & 7;
  int k   = kc * 32 + ((lane >> 4) << 3) + j;
  int col = ntile * 16 + (lane & 15);
  float wv = W[k * 256 + col];
  unsigned short hi = f32_to_bf16_rne(wv);
  float hif; { uint32_t hu = ((uint32_t)hi) << 16; __builtin_memcpy(&hif, &hu, 4); }
  wh[t] = hi;
  wl[t] = f32_to_bf16_rne(wv - hif);               // exact residual (Sterbenz)
}

// R7: back to the Pareto-best R0 structure (256 thr, 4 waves x 64 cols,
// occ-42% band, 957 us) with its two defects removed:
//  (a) the 64-VGPR default budget forced ~26 dwords/thread of loop spill
//      (R6 proved it: at VGPR 68 the 100 B/thr write traffic vanished);
//  (b) sched_barrier(0) per 4-chain batch existed only to protect (a).
// __launch_bounds__(256,4) -> waves/EU = 4 -> 128-VGPR budget: the ~90-110
// live regs fit with NO spill, and 128 regs is exactly the 4-waves/SIMD
// bucket = 16 waves/CU — the same 4-block LDS cap R0 already ran at, so
// occupancy does NOT drop (R6's lesson: never trade occupancy for regs).
// sched_barrier dropped so next-batch threefry + next-phase W loads hoist
// under the current VALU stream (R1's blowup was this hoist at budget 64).
// R5/R6's nt-interleave is abandoned: doubled LDS bank conflicts, no win.
__global__ __launch_bounds__(256, 4)
void rbm_kernel(const float* __restrict__ h,
                const unsigned short* __restrict__ Wh,
                const unsigned short* __restrict__ Wl,
                float* __restrict__ out,
                uint32_t i0, uint32_t i1, uint32_t l0, uint32_t l1) {
  __shared__ unsigned short Zbuf[2][ROWS * 256];   // 2 x 16 KB
  __shared__ uint32_t kbuf[22];                    // [0..1]=init key, [2+2s..]=step s key
  const int tid  = threadIdx.x;
  const int w    = tid >> 6;        // wave 0..3 -> cols [64w, 64w+64)
  const int lane = tid & 63;
  const int q    = lane >> 4;
  const int l15  = lane & 15;
  const int b    = blockIdx.x;
  const int cb   = w * 64;
  const int nbase = b * ROWS;

  if (tid < 11) {
    uint32_t a, c;
    tf2x32(l0, l1, 0u, (uint32_t)tid - 1u, a, c);  // step key E_{kloop}(0, tid-1)
    if (tid == 0) { a = i0; c = i1; }              // init key
    kbuf[2 * tid]     = a;
    kbuf[2 * tid + 1] = c;
  }

  float hreg[NT];
  #pragma unroll
  for (int nt = 0; nt < NT; ++nt) hreg[nt] = h[cb + nt * 16 + l15];

  f32x4 acc[MT][NT];
  #pragma unroll
  for (int mt = 0; mt < MT; ++mt)
    #pragma unroll
    for (int nt = 0; nt < NT; ++nt) acc[mt][nt] = (f32x4){0.f, 0.f, 0.f, 0.f};

  auto do_matmul = [&](const unsigned short* Zin) {  // acc = Z @ W (bf16 hi+lo)
    #pragma unroll
    for (int mt = 0; mt < MT; ++mt)
      #pragma unroll
      for (int nt = 0; nt < NT; ++nt) acc[mt][nt] = (f32x4){0.f, 0.f, 0.f, 0.f};
    #pragma unroll 2
    for (int kc = 0; kc < 8; ++kc) {
      short8 a[MT];
      #pragma unroll
      for (int mt = 0; mt < MT; ++mt) {
        int row = mt * 16 + l15;                       // A: m = lane&15
        int idx = row * 256 + ((((kc * 4 + q) ^ (row & 7)) << 3));  // k-chunk block
        a[mt] = *(const short8*)(Zin + idx);
      }
      #pragma unroll
      for (int nt = 0; nt < NT; ++nt) {
        int fidx = ((((NT * w + nt) * 8 + kc) * 64) + lane) * 8;
        short8 bh = *(const short8*)(Wh + fidx);
        short8 bl = *(const short8*)(Wl + fidx);
        #pragma unroll
        for (int mt = 0; mt < MT; ++mt)
          acc[mt][nt] = __builtin_amdgcn_mfma_f32_16x16x32_bf16(a[mt], bh, acc[mt][nt], 0, 0, 0);
        #pragma unroll
        for (int mt = 0; mt < MT; ++mt)
          acc[mt][nt] = __builtin_amdgcn_mfma_f32_16x16x32_bf16(a[mt], bl, acc[mt][nt], 0, 0, 0);
      }
    }
  };

  __syncthreads();   // kbuf visible to all waves

  // s = -1: bernoulli init (x = 0 -> p = 0.5 exactly) writes Z[0];
  // s = 0..9: matmul reads Z[s&1], sampling writes Z[(s+1)&1];
  // s = 10: final matmul only (reads Z[0] = final z) for the energy.
  #pragma unroll 1
  for (int s = -1; s <= 10; ++s) {
    if (s >= 0) do_matmul(Zbuf[s & 1]);
    if (s < 10) {
      unsigned short* Zout = Zbuf[(s + 1) & 1];
      const uint32_t kk0 = kbuf[2 * (s + 1)];        // uniform LDS broadcast
      const uint32_t kk1 = kbuf[2 * (s + 1) + 1];
      const bool isInit = (s < 0);
      #pragma unroll
      for (int mt = 0; mt < MT; ++mt) {
        #pragma unroll
        for (int nt = 0; nt < NT; ++nt) {
          const int dcol = cb + nt * 16 + l15;
          const int rowb = mt * 16 + q * 4;            // C/D: row = quad*4 + reg
          const uint32_t cbase = (uint32_t)((nbase + rowb) * 256 + dcol);
          // 4 independent threefry chains in flight (hides the dep chain)
          uint32_t bits[4];
          #pragma unroll
          for (int r = 0; r < 4; ++r) bits[r] = tf_bits(kk0, kk1, cbase + 256u * (uint32_t)r);
          #pragma unroll
          for (int r = 0; r < 4; ++r) {
            float u = __uint_as_float((bits[r] >> 9) | 0x3f800000u) - 1.0f;
            float x = isInit ? 0.0f : (acc[mt][nt][r] + hreg[nt]);
            float x2 = x * x;
            float sg = fmaf(x, fmaf(x2, fmaf(x2, 2.0833333333333333e-03f,
                                                 -2.0833333333333332e-02f), 0.25f), 0.5f);
            if (__builtin_expect((fabsf(u - sg) <= 1e-5f) || (fabsf(x) >= 0.12f), 0))
              sg = sigmoid_exact(x);
            Zout[zaddr(rowb + r, dcol)] = (u < sg) ? (unsigned short)0x3F80u : (unsigned short)0u;
          }
        }
      }
    }
    __syncthreads();   // sampling(s) writes visible before matmul(s+1) reads
  }

  // energy[n] = -(sum_d z*h + sum_d (z@W)*z); acc holds y = z@W, z in Zbuf[0]
  const unsigned short* Zfin = Zbuf[0];
  float rs[MT][4];
  #pragma unroll
  for (int mt = 0; mt < MT; ++mt) {
    #pragma unroll
    for (int r = 0; r < 4; ++r) {
      const int row = mt * 16 + q * 4 + r;
      float p = 0.f;
      #pragma unroll
      for (int nt = 0; nt < NT; ++nt) {
        const int dcol = cb + nt * 16 + l15;
        float z = (Zfin[zaddr(row, dcol)] != 0) ? 1.0f : 0.0f;
        p += z * (hreg[nt] + acc[mt][nt][r]);
      }
      p += __shfl_xor(p, 1);
      p += __shfl_xor(p, 2);
      p += __shfl_xor(p, 4);
      p += __shfl_xor(p, 8);
      rs[mt][r] = p;   // 16-lane group sum (this wave's 64 cols)
    }
  }
  __syncthreads();                      // Zbuf[1] reads long done -> reuse as esum
  float* esum = (float*)Zbuf[1];        // esum[row*4 + w]
  #pragma unroll
  for (int mt = 0; mt < MT; ++mt)
    #pragma unroll
    for (int r = 0; r < 4; ++r)
      if (l15 == 0) esum[(mt * 16 + q * 4 + r) * 4 + w] = rs[mt][r];
  __syncthreads();
  if (tid < ROWS) {
    float e = esum[tid * 4 + 0] + esum[tid * 4 + 1] + esum[tid * 4 + 2] + esum[tid * 4 + 3];
    out[nbase + tid] = -e;
  }
}

extern "C" void kernel_launch(void* const* d_in, const int* in_sizes, int n_in,
                              void* d_out, int out_size, void* d_ws, size_t ws_size,
                              hipStream_t stream) {
  const float* h = (const float*)d_in[0];
  const float* W = (const float*)d_in[1];
  float* out = (float*)d_out;
  unsigned short* wh = (unsigned short*)d_ws;      // 65536 bf16 = 128 KB
  unsigned short* wl = wh + 65536;                 // +128 KB

  prep_w<<<256, 256, 0, stream>>>(W, wh, wl);

  // Host-side key derivation (jax_threefry_partitionable=True semantics):
  // root = key(42) = (0,42); split -> k_init = E(0,0), k_loop = E(0,1).
  // Step keys are derived on-device (threads 0..10 per block, once).
  uint32_t i0, i1, l0, l1;
  tf2x32(0u, 42u, 0u, 0u, i0, i1);
  tf2x32(0u, 42u, 0u, 1u, l0, l1);

  rbm_kernel<<<NSAMP / ROWS, 256, 0, stream>>>(h, wh, wl, out, i0, i1, l0, l1);
}